// Round 1
// 157.138 us; speedup vs baseline: 1.0368x; 1.0368x over previous
//
#include <hip/hip_runtime.h>
#include <hip/hip_bf16.h>

typedef __bf16 bf16_t;
typedef __bf16 bf16x8 __attribute__((ext_vector_type(8)));
typedef __bf16 bf16x4 __attribute__((ext_vector_type(4)));
typedef short  s16x4  __attribute__((ext_vector_type(4)));
typedef float  f32x4  __attribute__((ext_vector_type(4)));

#define B_DIM 8
#define C_DIM 512
#define T_DIM 1024
#define NH 8
#define HD 64

// softmax scale^2 * log2(e), folded into Q at the qkv epilogue
#define QSCALE 0.180336880111112f

// v_mfma_f32_16x16x16_bf16 (gfx950 ISA §10): A/B = 4 bf16 (2 VGPRs),
// operand layout k=quad*4+j, m/n=l15; C row=quad*4+r, col=l15.
__device__ __forceinline__ f32x4 mfma16_bf16(bf16x4 a, bf16x4 b, f32x4 c) {
    return __builtin_amdgcn_mfma_f32_16x16x16bf16_1k(
        __builtin_bit_cast(s16x4, a), __builtin_bit_cast(s16x4, b), c, 0, 0, 0);
}

// raw barrier: make LDS writes visible, but do NOT drain vmcnt (prefetch
// loads stay in flight across the barrier — T4 style).
__device__ __forceinline__ void block_sync_lds() {
    asm volatile("s_waitcnt lgkmcnt(0)" ::: "memory");
    __builtin_amdgcn_s_barrier();
}

// ---------------------------------------------------------------------------
// Kernel 0: one-time weight conversion fp32 -> bf16.
// ---------------------------------------------------------------------------
__global__ __launch_bounds__(256) void prep_w(const float* __restrict__ w1,
                                              const float* __restrict__ w2,
                                              bf16_t* __restrict__ o1,
                                              bf16_t* __restrict__ o2)
{
    int tid = blockIdx.x * 256 + threadIdx.x;
    for (int p = 0; p < 4; ++p) {
        int q = tid + p * 65536;
        const f32x4* src;
        bf16x4* dst;
        int qq;
        if (q < 196608) { src = (const f32x4*)w1; dst = (bf16x4*)o1; qq = q; }
        else            { src = (const f32x4*)w2; dst = (bf16x4*)o2; qq = q - 196608; }
        f32x4 f = src[qq];
        bf16x4 h;
        for (int j = 0; j < 4; ++j) h[j] = (bf16_t)f[j];
        dst[qq] = h;
    }
}

// ---------------------------------------------------------------------------
// Kernel 1: GroupNorm.  x (b,c,t) fp32 -> n_t (b,t,c) bf16.  (unchanged)
// ---------------------------------------------------------------------------
__global__ __launch_bounds__(256) void gn_kernel(const float* __restrict__ x,
                                                 const float* __restrict__ gw,
                                                 const float* __restrict__ gb,
                                                 bf16_t* __restrict__ n_t)
{
    __shared__ bf16_t sX[16384];
    __shared__ float sred[8];
    int tid = threadIdx.x;
    int bb  = blockIdx.x >> 5;
    int g   = blockIdx.x & 31;
    const f32x4* xg4 = reinterpret_cast<const f32x4*>(x + (size_t)(bb * C_DIM + g * 16) * T_DIM);

    float s = 0.f, sq = 0.f;
    for (int i = 0; i < 16; ++i) {
        int v = tid + i * 256;
        f32x4 f = xg4[v];
        bf16x4 h;
        for (int j = 0; j < 4; ++j) {
            s += f[j]; sq += f[j] * f[j];
            h[j] = (bf16_t)f[j];
        }
        *reinterpret_cast<bf16x4*>(sX + v * 4) = h;
    }
    for (int off = 1; off < 64; off <<= 1) {
        s  += __shfl_xor(s, off);
        sq += __shfl_xor(sq, off);
    }
    int wv = tid >> 6;
    if ((tid & 63) == 0) { sred[wv * 2] = s; sred[wv * 2 + 1] = sq; }
    __syncthreads();
    s  = sred[0] + sred[2] + sred[4] + sred[6];
    sq = sred[1] + sred[3] + sred[5] + sred[7];
    float mean = s * (1.f / 16384.f);
    float var  = sq * (1.f / 16384.f) - mean * mean;
    float rs   = rsqrtf(var + 1e-5f);

    int hf = tid & 1;
    float aa[8], bbias[8];
    for (int j = 0; j < 8; ++j) {
        int c = hf * 8 + j;
        float av = gw[g * 16 + c] * rs;
        aa[j] = av;
        bbias[j] = gb[g * 16 + c] - mean * av;
    }
    bf16_t* ob = n_t + (size_t)bb * T_DIM * C_DIM + g * 16 + hf * 8;
    for (int p = 0; p < 8; ++p) {
        int t = (tid >> 1) + p * 128;
        bf16x8 o;
        for (int j = 0; j < 8; ++j) {
            float xv = (float)sX[(hf * 8 + j) * 1024 + t];
            o[j] = (bf16_t)(xv * aa[j] + bbias[j]);
        }
        *reinterpret_cast<bf16x8*>(ob + (size_t)t * C_DIM) = o;
    }
}

// ---------------------------------------------------------------------------
// Kernel 2: QKV GEMM.  Only change: fold softmax scale into Q (type==0).
// ---------------------------------------------------------------------------
__global__ __launch_bounds__(256) void qkv_gemm_kernel(
    const bf16_t* __restrict__ wqb, const float* __restrict__ bq,
    const bf16_t* __restrict__ n_t, bf16_t* __restrict__ qkv)
{
    __shared__ bf16_t sA[64 * 72];
    __shared__ bf16_t sB[128 * 72];
    int tid = threadIdx.x;
    int w = tid >> 6, lane = tid & 63, quad = lane >> 4, l15 = lane & 15;
    int bx = blockIdx.x;          // 0..23  (= h*3 + type)
    int t0 = blockIdx.y * 128;
    int bb = blockIdx.z;
    int o0 = bx * 64;
    const bf16_t* Ab = wqb + (size_t)o0 * C_DIM;
    const bf16_t* Bb = n_t + ((size_t)bb * T_DIM + t0) * C_DIM;

    f32x4 acc[2][4];
    for (int mt = 0; mt < 2; ++mt)
        for (int nt = 0; nt < 4; ++nt)
            acc[mt][nt] = f32x4{0.f, 0.f, 0.f, 0.f};
    int mw0 = (w >> 1) * 32;
    int nw0 = (w & 1) * 64;

    for (int k0 = 0; k0 < C_DIM; k0 += 64) {
        for (int i = 0; i < 2; ++i) {
            int v = tid + i * 256;
            int row = v >> 3, c8 = v & 7;
            *reinterpret_cast<bf16x8*>(sA + row * 72 + c8 * 8) =
                *reinterpret_cast<const bf16x8*>(Ab + (size_t)row * C_DIM + k0 + c8 * 8);
        }
        for (int i = 0; i < 4; ++i) {
            int v = tid + i * 256;
            int row = v >> 3, c8 = v & 7;
            *reinterpret_cast<bf16x8*>(sB + row * 72 + c8 * 8) =
                *reinterpret_cast<const bf16x8*>(Bb + (size_t)row * C_DIM + k0 + c8 * 8);
        }
        __syncthreads();
        for (int kk = 0; kk < 2; ++kk) {
            bf16x8 af[2], bfr[4];
            for (int mt = 0; mt < 2; ++mt)
                af[mt] = *reinterpret_cast<const bf16x8*>(sA + (mw0 + mt * 16 + l15) * 72 + kk * 32 + quad * 8);
            for (int nt = 0; nt < 4; ++nt)
                bfr[nt] = *reinterpret_cast<const bf16x8*>(sB + (nw0 + nt * 16 + l15) * 72 + kk * 32 + quad * 8);
            for (int mt = 0; mt < 2; ++mt)
                for (int nt = 0; nt < 4; ++nt)
                    acc[mt][nt] = __builtin_amdgcn_mfma_f32_16x16x32_bf16(af[mt], bfr[nt], acc[mt][nt], 0, 0, 0);
        }
        __syncthreads();
    }

    int h = bx / 3, type = bx % 3;
    size_t base = ((size_t)(bb * NH + h) * 3 + type) * (64 * 1024);

    if (type < 2) {
        float scl = (type == 0) ? QSCALE : 1.0f;
        for (int mt = 0; mt < 2; ++mt)
            for (int nt = 0; nt < 4; ++nt)
                for (int r = 0; r < 4; ++r) {
                    int mw = mw0 + mt * 16 + quad * 4 + r;
                    int tl = nw0 + nt * 16 + l15;
                    float v = (acc[mt][nt][r] + bq[o0 + mw]) * scl;
                    sB[tl * 72 + mw] = (bf16_t)v;
                }
        __syncthreads();
        for (int i = 0; i < 4; ++i) {
            int v = tid + i * 256;
            int tl = v >> 3, c8 = v & 7;
            bf16x8 d = *reinterpret_cast<const bf16x8*>(sB + tl * 72 + c8 * 8);
            *reinterpret_cast<bf16x8*>(qkv + base + (size_t)(t0 + tl) * 64 + c8 * 8) = d;
        }
    } else {
        for (int mt = 0; mt < 2; ++mt)
            for (int nt = 0; nt < 4; ++nt)
                for (int r = 0; r < 4; ++r) {
                    int mw = mw0 + mt * 16 + quad * 4 + r;
                    int tl = nw0 + nt * 16 + l15;
                    float v = acc[mt][nt][r] + bq[o0 + mw];
                    sB[mw * 136 + tl] = (bf16_t)v;
                }
        __syncthreads();
        for (int i = 0; i < 4; ++i) {
            int v = tid + i * 256;
            int cc = v >> 4, t8 = (v & 15) * 8;
            bf16x8 d = *reinterpret_cast<const bf16x8*>(sB + cc * 136 + t8);
            *reinterpret_cast<bf16x8*>(qkv + base + (size_t)cc * 1024 + t0 + t8) = d;
        }
    }
}

// ---------------------------------------------------------------------------
// Kernel 3: flash attention, round 10.
//   - scale pre-folded into Q (exp2 directly on S)
//   - row-sum on the MFMA pipe: L = mfma16(ones, pf, L); inv = 1/L[0]
//   - double-buffered LDS (2x18.4KB), ONE raw barrier per tile (lgkmcnt only,
//     vmcnt stays in flight across the barrier)
//   - two named prefetch register sets (A/B) -> static indexing, no WAR stall
//   - s_setprio(1) around the MFMA/softmax cluster
// ---------------------------------------------------------------------------
__global__ __launch_bounds__(256, 4) void attn_kernel(const bf16_t* __restrict__ qkv,
                                                      bf16_t* __restrict__ net_t)
{
    __shared__ bf16_t sK0[64 * 72];
    __shared__ bf16_t sV0[64 * 72];
    __shared__ bf16_t sK1[64 * 72];
    __shared__ bf16_t sV1[64 * 72];
    int tid = threadIdx.x;
    int w = tid >> 6, lane = tid & 63, quad = lane >> 4, l15 = lane & 15;
    int bh = blockIdx.x;
    int qt = blockIdx.y;
    size_t qb = (size_t)bh * 3 * 65536;
    const bf16_t* Qg = qkv + qb + (size_t)qt * 4096;
    const bf16_t* Kg = qkv + qb + 65536;
    const bf16_t* Vg = qkv + qb + 2 * 65536;

    // Q as B-operand (n=t=l15 within wave's 16 rows, k=c), in registers
    bf16x8 qf[2];
    for (int kk = 0; kk < 2; ++kk)
        qf[kk] = *reinterpret_cast<const bf16x8*>(Qg + (size_t)(w * 16 + l15) * 64 + kk * 32 + quad * 8);

    int vrow = tid >> 3;            // 0..31
    int vcol = (tid & 7) * 8;       // 0..56

    bf16x8 kA[2], vA[2], kB[2], vB[2];

    auto load_tiles = [&](bf16x8* kr, bf16x8* vr, int s0) {
        for (int i = 0; i < 2; ++i) {
            int r = vrow + i * 32;
            kr[i] = *reinterpret_cast<const bf16x8*>(Kg + (size_t)(s0 + r) * 64 + vcol);
            vr[i] = *reinterpret_cast<const bf16x8*>(Vg + (size_t)r * 1024 + s0 + vcol);
        }
    };
    auto write_tiles = [&](bf16_t* sKb, bf16_t* sVb, const bf16x8* kr, const bf16x8* vr) {
        for (int i = 0; i < 2; ++i) {
            int r = vrow + i * 32;
            *reinterpret_cast<bf16x8*>(sKb + r * 72 + vcol) = kr[i];
            *reinterpret_cast<bf16x8*>(sVb + r * 72 + vcol) = vr[i];
        }
    };

    f32x4 O[4];   // O^T: [ct] rows c=ct*16+quad*4+r, col t=l15
    for (int i = 0; i < 4; ++i) O[i] = f32x4{0.f, 0.f, 0.f, 0.f};
    f32x4 L = f32x4{0.f, 0.f, 0.f, 0.f};   // ones-matrix row sums (all rows equal)
    const bf16x4 kONES = bf16x4{(bf16_t)1.f, (bf16_t)1.f, (bf16_t)1.f, (bf16_t)1.f};

    auto compute_tile = [&](const bf16_t* sKb, const bf16_t* sVb) {
        __builtin_amdgcn_s_setprio(1);
        for (int mt = 0; mt < 4; ++mt) {
            // ---- S^T = K.Q^T for s-subtile mt (A=K rows s_local=l15) ----
            f32x4 S = f32x4{0.f, 0.f, 0.f, 0.f};
            for (int kk = 0; kk < 2; ++kk) {
                bf16x8 kf = *reinterpret_cast<const bf16x8*>(sKb + (mt * 16 + l15) * 72 + kk * 32 + quad * 8);
                S = __builtin_amdgcn_mfma_f32_16x16x32_bf16(kf, qf[kk], S, 0, 0, 0);
            }
            // ---- exp2 in-register (scale already folded into Q) ----
            bf16x4 pf;
            for (int r = 0; r < 4; ++r)
                pf[r] = (bf16_t)__builtin_amdgcn_exp2f(S[r]);
            // ---- row-sum on the MFMA pipe ----
            L = mfma16_bf16(kONES, pf, L);
            // ---- O^T += V.P^T (contraction over 16 s; A=V rows c=l15) ----
            for (int ct = 0; ct < 4; ++ct) {
                bf16x4 vf = *reinterpret_cast<const bf16x4*>(sVb + (ct * 16 + l15) * 72 + mt * 16 + quad * 4);
                O[ct] = mfma16_bf16(vf, pf, O[ct]);
            }
        }
        __builtin_amdgcn_s_setprio(0);
    };

    // prologue: tile0 -> buf0, prefetch tile1 into B
    load_tiles(kA, vA, 0);
    write_tiles(sK0, sV0, kA, vA);
    load_tiles(kB, vB, 64);
    block_sync_lds();

    for (int st2 = 0; st2 < 8; ++st2) {
        // even tile t=2*st2 from buf0; stage tile t+1 (regs B) -> buf1
        write_tiles(sK1, sV1, kB, vB);
        if (st2 < 7) load_tiles(kA, vA, (2 * st2 + 2) * 64);
        compute_tile(sK0, sV0);
        block_sync_lds();
        // odd tile t+1 from buf1; stage tile t+2 (regs A) -> buf0
        if (st2 < 7) {
            write_tiles(sK0, sV0, kA, vA);
            load_tiles(kB, vB, (2 * st2 + 3) * 64);
        }
        compute_tile(sK1, sV1);
        if (st2 < 7) block_sync_lds();
    }

    // every element of L equals the full row-sum for col t=l15
    float inv = 1.f / L[0];

    int bb = bh >> 3, h = bh & 7;
    int t = qt * 64 + w * 16 + l15;
    bf16_t* orow = net_t + ((size_t)bb * T_DIM + t) * C_DIM + h * 64;
    for (int ct = 0; ct < 4; ++ct) {
        bf16x4 o4;
        for (int r = 0; r < 4; ++r) o4[r] = (bf16_t)(O[ct][r] * inv);
        *reinterpret_cast<bf16x4*>(orow + ct * 16 + quad * 4) = o4;
    }
}

// ---------------------------------------------------------------------------
// Kernel 4: out GEMM + bias + residual (unchanged).
// ---------------------------------------------------------------------------
__global__ __launch_bounds__(256) void out_gemm_kernel(
    const bf16_t* __restrict__ wob, const float* __restrict__ bo,
    const bf16_t* __restrict__ net_t, const float* __restrict__ x,
    float* __restrict__ out)
{
    __shared__ bf16_t sA[64 * 72];
    __shared__ bf16_t sB[128 * 72];
    int tid = threadIdx.x;
    int w = tid >> 6, lane = tid & 63, quad = lane >> 4, l15 = lane & 15;
    int o0 = blockIdx.x * 64;
    int t0 = blockIdx.y * 128;
    int bb = blockIdx.z;
    const bf16_t* Ab = wob + (size_t)o0 * C_DIM;
    const bf16_t* Bb = net_t + ((size_t)bb * T_DIM + t0) * C_DIM;

    f32x4 acc[2][4];
    for (int mt = 0; mt < 2; ++mt)
        for (int nt = 0; nt < 4; ++nt)
            acc[mt][nt] = f32x4{0.f, 0.f, 0.f, 0.f};
    int mw0 = (w >> 1) * 32;
    int nw0 = (w & 1) * 64;

    for (int k0 = 0; k0 < C_DIM; k0 += 64) {
        for (int i = 0; i < 2; ++i) {
            int v = tid + i * 256;
            int row = v >> 3, c8 = v & 7;
            *reinterpret_cast<bf16x8*>(sA + row * 72 + c8 * 8) =
                *reinterpret_cast<const bf16x8*>(Ab + (size_t)row * C_DIM + k0 + c8 * 8);
        }
        for (int i = 0; i < 4; ++i) {
            int v = tid + i * 256;
            int row = v >> 3, c8 = v & 7;
            *reinterpret_cast<bf16x8*>(sB + row * 72 + c8 * 8) =
                *reinterpret_cast<const bf16x8*>(Bb + (size_t)row * C_DIM + k0 + c8 * 8);
        }
        __syncthreads();
        for (int kk = 0; kk < 2; ++kk) {
            bf16x8 af[2], bfr[4];
            for (int mt = 0; mt < 2; ++mt)
                af[mt] = *reinterpret_cast<const bf16x8*>(sA + (mw0 + mt * 16 + l15) * 72 + kk * 32 + quad * 8);
            for (int nt = 0; nt < 4; ++nt)
                bfr[nt] = *reinterpret_cast<const bf16x8*>(sB + (nw0 + nt * 16 + l15) * 72 + kk * 32 + quad * 8);
            for (int mt = 0; mt < 2; ++mt)
                for (int nt = 0; nt < 4; ++nt)
                    acc[mt][nt] = __builtin_amdgcn_mfma_f32_16x16x32_bf16(af[mt], bfr[nt], acc[mt][nt], 0, 0, 0);
        }
        __syncthreads();
    }

    for (int mt = 0; mt < 2; ++mt)
        for (int nt = 0; nt < 4; ++nt)
            for (int r = 0; r < 4; ++r) {
                int o = o0 + mw0 + mt * 16 + quad * 4 + r;
                int t = t0 + nw0 + nt * 16 + l15;
                size_t idx = ((size_t)bb * C_DIM + o) * T_DIM + t;
                out[idx] = acc[mt][nt][r] + bo[o] + x[idx];
            }
}

// ---------------------------------------------------------------------------
extern "C" void kernel_launch(void* const* d_in, const int* in_sizes, int n_in,
                              void* d_out, int out_size, void* d_ws, size_t ws_size,
                              hipStream_t stream)
{
    const float* x     = (const float*)d_in[0];
    const float* gn_w  = (const float*)d_in[1];
    const float* gn_b  = (const float*)d_in[2];
    const float* qkv_w = (const float*)d_in[3];
    const float* qkv_b = (const float*)d_in[4];
    const float* out_w = (const float*)d_in[5];
    const float* out_b = (const float*)d_in[6];
    float* out = (float*)d_out;

    // ws layout (bf16): n_t 8MB | qkv 24MB | net_t 8MB | wqb 1.5MB | wob 0.5MB
    char* ws = (char*)d_ws;
    bf16_t* n_t   = (bf16_t*)(ws);
    bf16_t* qkv   = (bf16_t*)(ws + 8388608);
    bf16_t* net_t = (bf16_t*)(ws + 33554432);
    bf16_t* wqb   = (bf16_t*)(ws + 41943040);
    bf16_t* wob   = (bf16_t*)(ws + 41943040 + 1572864);

    prep_w<<<dim3(256), 256, 0, stream>>>(qkv_w, out_w, wqb, wob);
    gn_kernel<<<dim3(256), 256, 0, stream>>>(x, gn_w, gn_b, n_t);
    qkv_gemm_kernel<<<dim3(24, 8, 8), 256, 0, stream>>>(wqb, qkv_b, n_t, qkv);
    attn_kernel<<<dim3(64, 16), 256, 0, stream>>>(qkv, net_t);
    out_gemm_kernel<<<dim3(8, 8, 8), 256, 0, stream>>>(wob, out_b, net_t, x, out);
}

// Round 2
// 152.877 us; speedup vs baseline: 1.0657x; 1.0279x over previous
//
#include <hip/hip_runtime.h>
#include <hip/hip_bf16.h>

typedef __bf16 bf16_t;
typedef __bf16 bf16x8 __attribute__((ext_vector_type(8)));
typedef __bf16 bf16x4 __attribute__((ext_vector_type(4)));
typedef short  s16x4  __attribute__((ext_vector_type(4)));
typedef float  f32x4  __attribute__((ext_vector_type(4)));

#define B_DIM 8
#define C_DIM 512
#define T_DIM 1024
#define NH 8
#define HD 64

// softmax scale^2 * log2(e), folded into Q at the qkv epilogue
#define QSCALE 0.180336880111112f

// v_mfma_f32_16x16x16_bf16 (gfx950 ISA §10): A/B = 4 bf16 (2 VGPRs),
// operand layout k=quad*4+j, m/n=l15; C row=quad*4+r, col=l15.
__device__ __forceinline__ f32x4 mfma16_bf16(bf16x4 a, bf16x4 b, f32x4 c) {
    return __builtin_amdgcn_mfma_f32_16x16x16bf16_1k(
        __builtin_bit_cast(s16x4, a), __builtin_bit_cast(s16x4, b), c, 0, 0, 0);
}

// raw barrier: make LDS writes visible, but do NOT drain vmcnt (prefetch
// loads stay in flight across the barrier — T4 style).
__device__ __forceinline__ void block_sync_lds() {
    asm volatile("s_waitcnt lgkmcnt(0)" ::: "memory");
    __builtin_amdgcn_s_barrier();
}

// ---------------------------------------------------------------------------
// Kernel 0: one-time weight conversion fp32 -> bf16.
// ---------------------------------------------------------------------------
__global__ __launch_bounds__(256) void prep_w(const float* __restrict__ w1,
                                              const float* __restrict__ w2,
                                              bf16_t* __restrict__ o1,
                                              bf16_t* __restrict__ o2)
{
    int tid = blockIdx.x * 256 + threadIdx.x;
    for (int p = 0; p < 4; ++p) {
        int q = tid + p * 65536;
        const f32x4* src;
        bf16x4* dst;
        int qq;
        if (q < 196608) { src = (const f32x4*)w1; dst = (bf16x4*)o1; qq = q; }
        else            { src = (const f32x4*)w2; dst = (bf16x4*)o2; qq = q - 196608; }
        f32x4 f = src[qq];
        bf16x4 h;
        for (int j = 0; j < 4; ++j) h[j] = (bf16_t)f[j];
        dst[qq] = h;
    }
}

// ---------------------------------------------------------------------------
// Kernel 1: GroupNorm.  x (b,c,t) fp32 -> n_t (b,t,c) bf16.  (unchanged)
// ---------------------------------------------------------------------------
__global__ __launch_bounds__(256) void gn_kernel(const float* __restrict__ x,
                                                 const float* __restrict__ gw,
                                                 const float* __restrict__ gb,
                                                 bf16_t* __restrict__ n_t)
{
    __shared__ bf16_t sX[16384];
    __shared__ float sred[8];
    int tid = threadIdx.x;
    int bb  = blockIdx.x >> 5;
    int g   = blockIdx.x & 31;
    const f32x4* xg4 = reinterpret_cast<const f32x4*>(x + (size_t)(bb * C_DIM + g * 16) * T_DIM);

    float s = 0.f, sq = 0.f;
    for (int i = 0; i < 16; ++i) {
        int v = tid + i * 256;
        f32x4 f = xg4[v];
        bf16x4 h;
        for (int j = 0; j < 4; ++j) {
            s += f[j]; sq += f[j] * f[j];
            h[j] = (bf16_t)f[j];
        }
        *reinterpret_cast<bf16x4*>(sX + v * 4) = h;
    }
    for (int off = 1; off < 64; off <<= 1) {
        s  += __shfl_xor(s, off);
        sq += __shfl_xor(sq, off);
    }
    int wv = tid >> 6;
    if ((tid & 63) == 0) { sred[wv * 2] = s; sred[wv * 2 + 1] = sq; }
    __syncthreads();
    s  = sred[0] + sred[2] + sred[4] + sred[6];
    sq = sred[1] + sred[3] + sred[5] + sred[7];
    float mean = s * (1.f / 16384.f);
    float var  = sq * (1.f / 16384.f) - mean * mean;
    float rs   = rsqrtf(var + 1e-5f);

    int hf = tid & 1;
    float aa[8], bbias[8];
    for (int j = 0; j < 8; ++j) {
        int c = hf * 8 + j;
        float av = gw[g * 16 + c] * rs;
        aa[j] = av;
        bbias[j] = gb[g * 16 + c] - mean * av;
    }
    bf16_t* ob = n_t + (size_t)bb * T_DIM * C_DIM + g * 16 + hf * 8;
    for (int p = 0; p < 8; ++p) {
        int t = (tid >> 1) + p * 128;
        bf16x8 o;
        for (int j = 0; j < 8; ++j) {
            float xv = (float)sX[(hf * 8 + j) * 1024 + t];
            o[j] = (bf16_t)(xv * aa[j] + bbias[j]);
        }
        *reinterpret_cast<bf16x8*>(ob + (size_t)t * C_DIM) = o;
    }
}

// ---------------------------------------------------------------------------
// Kernel 2: QKV GEMM (scale folded into Q for type==0).
// ---------------------------------------------------------------------------
__global__ __launch_bounds__(256) void qkv_gemm_kernel(
    const bf16_t* __restrict__ wqb, const float* __restrict__ bq,
    const bf16_t* __restrict__ n_t, bf16_t* __restrict__ qkv)
{
    __shared__ bf16_t sA[64 * 72];
    __shared__ bf16_t sB[128 * 72];
    int tid = threadIdx.x;
    int w = tid >> 6, lane = tid & 63, quad = lane >> 4, l15 = lane & 15;
    int bx = blockIdx.x;          // 0..23  (= h*3 + type)
    int t0 = blockIdx.y * 128;
    int bb = blockIdx.z;
    int o0 = bx * 64;
    const bf16_t* Ab = wqb + (size_t)o0 * C_DIM;
    const bf16_t* Bb = n_t + ((size_t)bb * T_DIM + t0) * C_DIM;

    f32x4 acc[2][4];
    for (int mt = 0; mt < 2; ++mt)
        for (int nt = 0; nt < 4; ++nt)
            acc[mt][nt] = f32x4{0.f, 0.f, 0.f, 0.f};
    int mw0 = (w >> 1) * 32;
    int nw0 = (w & 1) * 64;

    for (int k0 = 0; k0 < C_DIM; k0 += 64) {
        for (int i = 0; i < 2; ++i) {
            int v = tid + i * 256;
            int row = v >> 3, c8 = v & 7;
            *reinterpret_cast<bf16x8*>(sA + row * 72 + c8 * 8) =
                *reinterpret_cast<const bf16x8*>(Ab + (size_t)row * C_DIM + k0 + c8 * 8);
        }
        for (int i = 0; i < 4; ++i) {
            int v = tid + i * 256;
            int row = v >> 3, c8 = v & 7;
            *reinterpret_cast<bf16x8*>(sB + row * 72 + c8 * 8) =
                *reinterpret_cast<const bf16x8*>(Bb + (size_t)row * C_DIM + k0 + c8 * 8);
        }
        __syncthreads();
        for (int kk = 0; kk < 2; ++kk) {
            bf16x8 af[2], bfr[4];
            for (int mt = 0; mt < 2; ++mt)
                af[mt] = *reinterpret_cast<const bf16x8*>(sA + (mw0 + mt * 16 + l15) * 72 + kk * 32 + quad * 8);
            for (int nt = 0; nt < 4; ++nt)
                bfr[nt] = *reinterpret_cast<const bf16x8*>(sB + (nw0 + nt * 16 + l15) * 72 + kk * 32 + quad * 8);
            for (int mt = 0; mt < 2; ++mt)
                for (int nt = 0; nt < 4; ++nt)
                    acc[mt][nt] = __builtin_amdgcn_mfma_f32_16x16x32_bf16(af[mt], bfr[nt], acc[mt][nt], 0, 0, 0);
        }
        __syncthreads();
    }

    int h = bx / 3, type = bx % 3;
    size_t base = ((size_t)(bb * NH + h) * 3 + type) * (64 * 1024);

    if (type < 2) {
        float scl = (type == 0) ? QSCALE : 1.0f;
        for (int mt = 0; mt < 2; ++mt)
            for (int nt = 0; nt < 4; ++nt)
                for (int r = 0; r < 4; ++r) {
                    int mw = mw0 + mt * 16 + quad * 4 + r;
                    int tl = nw0 + nt * 16 + l15;
                    float v = (acc[mt][nt][r] + bq[o0 + mw]) * scl;
                    sB[tl * 72 + mw] = (bf16_t)v;
                }
        __syncthreads();
        for (int i = 0; i < 4; ++i) {
            int v = tid + i * 256;
            int tl = v >> 3, c8 = v & 7;
            bf16x8 d = *reinterpret_cast<const bf16x8*>(sB + tl * 72 + c8 * 8);
            *reinterpret_cast<bf16x8*>(qkv + base + (size_t)(t0 + tl) * 64 + c8 * 8) = d;
        }
    } else {
        for (int mt = 0; mt < 2; ++mt)
            for (int nt = 0; nt < 4; ++nt)
                for (int r = 0; r < 4; ++r) {
                    int mw = mw0 + mt * 16 + quad * 4 + r;
                    int tl = nw0 + nt * 16 + l15;
                    float v = acc[mt][nt][r] + bq[o0 + mw];
                    sB[mw * 136 + tl] = (bf16_t)v;
                }
        __syncthreads();
        for (int i = 0; i < 4; ++i) {
            int v = tid + i * 256;
            int cc = v >> 4, t8 = (v & 15) * 8;
            bf16x8 d = *reinterpret_cast<const bf16x8*>(sB + cc * 136 + t8);
            *reinterpret_cast<bf16x8*>(qkv + base + (size_t)cc * 1024 + t0 + t8) = d;
        }
    }
}

// ---------------------------------------------------------------------------
// Kernel 3: flash attention, round 11.
// LDS-traffic halving: block now covers 128 t (grid.y 16->8); each wave owns
// TWO t-tiles (32 rows). Every K-fragment and V-fragment LDS read now feeds
// two MFMAs, halving LDS read bytes per unit work; K/V staging per bh also
// halves (8 blocks re-stage instead of 16). Double-buffered LDS, one raw
// barrier (lgkmcnt-only) per tile, row-sum on the MFMA pipe, setprio(1).
// ---------------------------------------------------------------------------
__global__ __launch_bounds__(256, 2) void attn_kernel(const bf16_t* __restrict__ qkv,
                                                      bf16_t* __restrict__ net_t)
{
    __shared__ bf16_t sK0[64 * 72];
    __shared__ bf16_t sV0[64 * 72];
    __shared__ bf16_t sK1[64 * 72];
    __shared__ bf16_t sV1[64 * 72];
    int tid = threadIdx.x;
    int w = tid >> 6, lane = tid & 63, quad = lane >> 4, l15 = lane & 15;
    int bh = blockIdx.x;
    int qt = blockIdx.y;                 // 0..7, 128 t-rows per block
    size_t qb = (size_t)bh * 3 * 65536;
    const bf16_t* Qg = qkv + qb + (size_t)qt * 8192;   // 128 rows x 64
    const bf16_t* Kg = qkv + qb + 65536;
    const bf16_t* Vg = qkv + qb + 2 * 65536;

    // Q as B-operand (n=t=l15 within each 16-row t-tile, k=c), in registers.
    // tt=0: rows [w*16, w*16+16), tt=1: rows [64+w*16, 64+w*16+16)
    bf16x8 qf[2][2];
    for (int tt = 0; tt < 2; ++tt)
        for (int kk = 0; kk < 2; ++kk)
            qf[tt][kk] = *reinterpret_cast<const bf16x8*>(
                Qg + (size_t)(tt * 64 + w * 16 + l15) * 64 + kk * 32 + quad * 8);

    int vrow = tid >> 3;            // 0..31
    int vcol = (tid & 7) * 8;       // 0..56

    bf16x8 kA[2], vA[2], kB[2], vB[2];

    auto load_tiles = [&](bf16x8* kr, bf16x8* vr, int s0) {
        for (int i = 0; i < 2; ++i) {
            int r = vrow + i * 32;
            kr[i] = *reinterpret_cast<const bf16x8*>(Kg + (size_t)(s0 + r) * 64 + vcol);
            vr[i] = *reinterpret_cast<const bf16x8*>(Vg + (size_t)r * 1024 + s0 + vcol);
        }
    };
    auto write_tiles = [&](bf16_t* sKb, bf16_t* sVb, const bf16x8* kr, const bf16x8* vr) {
        for (int i = 0; i < 2; ++i) {
            int r = vrow + i * 32;
            *reinterpret_cast<bf16x8*>(sKb + r * 72 + vcol) = kr[i];
            *reinterpret_cast<bf16x8*>(sVb + r * 72 + vcol) = vr[i];
        }
    };

    f32x4 O0[4], O1[4];   // O^T per t-tile: rows c=ct*16+quad*4+r, col t=l15
    for (int i = 0; i < 4; ++i) {
        O0[i] = f32x4{0.f, 0.f, 0.f, 0.f};
        O1[i] = f32x4{0.f, 0.f, 0.f, 0.f};
    }
    f32x4 L0 = f32x4{0.f, 0.f, 0.f, 0.f};
    f32x4 L1 = f32x4{0.f, 0.f, 0.f, 0.f};
    const bf16x4 kONES = bf16x4{(bf16_t)1.f, (bf16_t)1.f, (bf16_t)1.f, (bf16_t)1.f};

    auto compute_tile = [&](const bf16_t* sKb, const bf16_t* sVb) {
        __builtin_amdgcn_s_setprio(1);
        for (int mt = 0; mt < 4; ++mt) {
            // ---- K fragment read ONCE, feeds both t-tiles ----
            const bf16_t* krow = sKb + (mt * 16 + l15) * 72 + quad * 8;
            bf16x8 kf0 = *reinterpret_cast<const bf16x8*>(krow);
            bf16x8 kf1 = *reinterpret_cast<const bf16x8*>(krow + 32);
            f32x4 S0 = f32x4{0.f, 0.f, 0.f, 0.f};
            f32x4 S1 = f32x4{0.f, 0.f, 0.f, 0.f};
            S0 = __builtin_amdgcn_mfma_f32_16x16x32_bf16(kf0, qf[0][0], S0, 0, 0, 0);
            S1 = __builtin_amdgcn_mfma_f32_16x16x32_bf16(kf0, qf[1][0], S1, 0, 0, 0);
            S0 = __builtin_amdgcn_mfma_f32_16x16x32_bf16(kf1, qf[0][1], S0, 0, 0, 0);
            S1 = __builtin_amdgcn_mfma_f32_16x16x32_bf16(kf1, qf[1][1], S1, 0, 0, 0);
            // ---- exp2 in-register (scale folded into Q) ----
            bf16x4 pf0, pf1;
            for (int r = 0; r < 4; ++r) {
                pf0[r] = (bf16_t)__builtin_amdgcn_exp2f(S0[r]);
                pf1[r] = (bf16_t)__builtin_amdgcn_exp2f(S1[r]);
            }
            // ---- row-sums on the MFMA pipe ----
            L0 = mfma16_bf16(kONES, pf0, L0);
            L1 = mfma16_bf16(kONES, pf1, L1);
            // ---- O^T += V.P^T; V fragment read ONCE, feeds both t-tiles ----
            for (int ct = 0; ct < 4; ++ct) {
                bf16x4 vf = *reinterpret_cast<const bf16x4*>(sVb + (ct * 16 + l15) * 72 + mt * 16 + quad * 4);
                O0[ct] = mfma16_bf16(vf, pf0, O0[ct]);
                O1[ct] = mfma16_bf16(vf, pf1, O1[ct]);
            }
        }
        __builtin_amdgcn_s_setprio(0);
    };

    // prologue: tile0 -> buf0, prefetch tile1 into B
    load_tiles(kA, vA, 0);
    write_tiles(sK0, sV0, kA, vA);
    load_tiles(kB, vB, 64);
    block_sync_lds();

    for (int st2 = 0; st2 < 8; ++st2) {
        // even tile t=2*st2 from buf0; stage tile t+1 (regs B) -> buf1
        write_tiles(sK1, sV1, kB, vB);
        if (st2 < 7) load_tiles(kA, vA, (2 * st2 + 2) * 64);
        compute_tile(sK0, sV0);
        block_sync_lds();
        // odd tile t+1 from buf1; stage tile t+2 (regs A) -> buf0
        if (st2 < 7) {
            write_tiles(sK0, sV0, kA, vA);
            load_tiles(kB, vB, (2 * st2 + 3) * 64);
        }
        compute_tile(sK1, sV1);
        if (st2 < 7) block_sync_lds();
    }

    // every element of L equals the full row-sum for col t=l15
    float inv0 = 1.f / L0[0];
    float inv1 = 1.f / L1[0];

    int bb = bh >> 3, h = bh & 7;
    int tbase = qt * 128 + w * 16 + l15;
    bf16_t* orow0 = net_t + ((size_t)bb * T_DIM + tbase) * C_DIM + h * 64;
    bf16_t* orow1 = net_t + ((size_t)bb * T_DIM + tbase + 64) * C_DIM + h * 64;
    for (int ct = 0; ct < 4; ++ct) {
        bf16x4 o4, o5;
        for (int r = 0; r < 4; ++r) {
            o4[r] = (bf16_t)(O0[ct][r] * inv0);
            o5[r] = (bf16_t)(O1[ct][r] * inv1);
        }
        *reinterpret_cast<bf16x4*>(orow0 + ct * 16 + quad * 4) = o4;
        *reinterpret_cast<bf16x4*>(orow1 + ct * 16 + quad * 4) = o5;
    }
}

// ---------------------------------------------------------------------------
// Kernel 4: out GEMM + bias + residual (unchanged).
// ---------------------------------------------------------------------------
__global__ __launch_bounds__(256) void out_gemm_kernel(
    const bf16_t* __restrict__ wob, const float* __restrict__ bo,
    const bf16_t* __restrict__ net_t, const float* __restrict__ x,
    float* __restrict__ out)
{
    __shared__ bf16_t sA[64 * 72];
    __shared__ bf16_t sB[128 * 72];
    int tid = threadIdx.x;
    int w = tid >> 6, lane = tid & 63, quad = lane >> 4, l15 = lane & 15;
    int o0 = blockIdx.x * 64;
    int t0 = blockIdx.y * 128;
    int bb = blockIdx.z;
    const bf16_t* Ab = wob + (size_t)o0 * C_DIM;
    const bf16_t* Bb = net_t + ((size_t)bb * T_DIM + t0) * C_DIM;

    f32x4 acc[2][4];
    for (int mt = 0; mt < 2; ++mt)
        for (int nt = 0; nt < 4; ++nt)
            acc[mt][nt] = f32x4{0.f, 0.f, 0.f, 0.f};
    int mw0 = (w >> 1) * 32;
    int nw0 = (w & 1) * 64;

    for (int k0 = 0; k0 < C_DIM; k0 += 64) {
        for (int i = 0; i < 2; ++i) {
            int v = tid + i * 256;
            int row = v >> 3, c8 = v & 7;
            *reinterpret_cast<bf16x8*>(sA + row * 72 + c8 * 8) =
                *reinterpret_cast<const bf16x8*>(Ab + (size_t)row * C_DIM + k0 + c8 * 8);
        }
        for (int i = 0; i < 4; ++i) {
            int v = tid + i * 256;
            int row = v >> 3, c8 = v & 7;
            *reinterpret_cast<bf16x8*>(sB + row * 72 + c8 * 8) =
                *reinterpret_cast<const bf16x8*>(Bb + (size_t)row * C_DIM + k0 + c8 * 8);
        }
        __syncthreads();
        for (int kk = 0; kk < 2; ++kk) {
            bf16x8 af[2], bfr[4];
            for (int mt = 0; mt < 2; ++mt)
                af[mt] = *reinterpret_cast<const bf16x8*>(sA + (mw0 + mt * 16 + l15) * 72 + kk * 32 + quad * 8);
            for (int nt = 0; nt < 4; ++nt)
                bfr[nt] = *reinterpret_cast<const bf16x8*>(sB + (nw0 + nt * 16 + l15) * 72 + kk * 32 + quad * 8);
            for (int mt = 0; mt < 2; ++mt)
                for (int nt = 0; nt < 4; ++nt)
                    acc[mt][nt] = __builtin_amdgcn_mfma_f32_16x16x32_bf16(af[mt], bfr[nt], acc[mt][nt], 0, 0, 0);
        }
        __syncthreads();
    }

    for (int mt = 0; mt < 2; ++mt)
        for (int nt = 0; nt < 4; ++nt)
            for (int r = 0; r < 4; ++r) {
                int o = o0 + mw0 + mt * 16 + quad * 4 + r;
                int t = t0 + nw0 + nt * 16 + l15;
                size_t idx = ((size_t)bb * C_DIM + o) * T_DIM + t;
                out[idx] = acc[mt][nt][r] + bo[o] + x[idx];
            }
}

// ---------------------------------------------------------------------------
extern "C" void kernel_launch(void* const* d_in, const int* in_sizes, int n_in,
                              void* d_out, int out_size, void* d_ws, size_t ws_size,
                              hipStream_t stream)
{
    const float* x     = (const float*)d_in[0];
    const float* gn_w  = (const float*)d_in[1];
    const float* gn_b  = (const float*)d_in[2];
    const float* qkv_w = (const float*)d_in[3];
    const float* qkv_b = (const float*)d_in[4];
    const float* out_w = (const float*)d_in[5];
    const float* out_b = (const float*)d_in[6];
    float* out = (float*)d_out;

    // ws layout (bf16): n_t 8MB | qkv 24MB | net_t 8MB | wqb 1.5MB | wob 0.5MB
    char* ws = (char*)d_ws;
    bf16_t* n_t   = (bf16_t*)(ws);
    bf16_t* qkv   = (bf16_t*)(ws + 8388608);
    bf16_t* net_t = (bf16_t*)(ws + 33554432);
    bf16_t* wqb   = (bf16_t*)(ws + 41943040);
    bf16_t* wob   = (bf16_t*)(ws + 41943040 + 1572864);

    prep_w<<<dim3(256), 256, 0, stream>>>(qkv_w, out_w, wqb, wob);
    gn_kernel<<<dim3(256), 256, 0, stream>>>(x, gn_w, gn_b, n_t);
    qkv_gemm_kernel<<<dim3(24, 8, 8), 256, 0, stream>>>(wqb, qkv_b, n_t, qkv);
    attn_kernel<<<dim3(64, 8), 256, 0, stream>>>(qkv, net_t);
    out_gemm_kernel<<<dim3(8, 8, 8), 256, 0, stream>>>(wob, out_b, net_t, x, out);
}